// Round 7
// baseline (473.901 us; speedup 1.0000x reference)
//
#include <hip/hip_runtime.h>
#include <hip/hip_bf16.h>
#include <stdint.h>

#define M_DIM 4096
#define K_DIM 4096
#define N_DIM 2048
#define B_DIM 4
#define NNZ_PER_ROW 409
#define NNZ_TOT (M_DIM * NNZ_PER_ROW)

typedef unsigned short u16;
typedef short short8 __attribute__((ext_vector_type(8)));
typedef float f32x4 __attribute__((ext_vector_type(4)));

__device__ __forceinline__ u16 f2bf(float f) {
    __hip_bfloat16 h = __float2bfloat16(f);
    u16 s;
    __builtin_memcpy(&s, &h, 2);
    return s;
}

// async global->LDS, 16 bytes per lane; LDS dest = wave-uniform base + lane*16
__device__ __forceinline__ void lds16(const u16* g, u16* l) {
    __builtin_amdgcn_global_load_lds(
        (__attribute__((address_space(1))) void*)g,
        (__attribute__((address_space(3))) void*)l,
        16, 0, 0);
}

// ---------------------------------------------------------------------------
// Kernel 1: x fp32 -> bf16. Each lane: 32 B read (2x float4), 16 B write.
// ---------------------------------------------------------------------------
__global__ void cvt_x(const float* __restrict__ in, u16* __restrict__ out) {
    int i = blockIdx.x * blockDim.x + threadIdx.x;  // 8 elements per thread
    float4 a = reinterpret_cast<const float4*>(in)[2 * i];
    float4 b = reinterpret_cast<const float4*>(in)[2 * i + 1];
    union { u16 u[8]; uint4 v; } o;
    o.u[0] = f2bf(a.x); o.u[1] = f2bf(a.y); o.u[2] = f2bf(a.z); o.u[3] = f2bf(a.w);
    o.u[4] = f2bf(b.x); o.u[5] = f2bf(b.y); o.u[6] = f2bf(b.z); o.u[7] = f2bf(b.w);
    reinterpret_cast<uint4*>(out)[i] = o.v;
}

// ---------------------------------------------------------------------------
// Kernel 2: CSR row -> dense bf16 W row, one block per row.
// ---------------------------------------------------------------------------
__global__ __launch_bounds__(256) void scatter_w(const float* __restrict__ vals,
                                                 const int* __restrict__ cols,
                                                 u16* __restrict__ W) {
    __shared__ float row[K_DIM];  // 16 KB
    const int t = threadIdx.x;
    const int m = blockIdx.x;
#pragma unroll
    for (int c = t; c < K_DIM; c += 256) row[c] = 0.0f;
    __syncthreads();
    const int base = m * NNZ_PER_ROW;
    for (int j = t; j < NNZ_PER_ROW; j += 256)
        atomicAdd(&row[cols[base + j]], vals[base + j]);
    __syncthreads();
    u16* Wr = W + (size_t)m * K_DIM + t * 16;
#pragma unroll
    for (int h = 0; h < 2; ++h) {
        union { u16 u[8]; uint4 v; } o;
#pragma unroll
        for (int e = 0; e < 8; ++e) o.u[e] = f2bf(row[t * 16 + h * 8 + e]);
        reinterpret_cast<uint4*>(Wr)[h] = o.v;
    }
}

// ---------------------------------------------------------------------------
// Kernel 3: NT GEMM, 256x256 tile, BK=64, 16x16x32 MFMA (R3's 0-conflict
// fragment pattern), 2 relaxed barriers/K-tile + counted-lgkm interleave (R7).
//   Findings driving this: (1) 32x32 fragments (row=lane&31) pay a constant
//   +4cyc/ds_read_b128 (2.517e7 conflicts, invariant under swizzle/barriers);
//   16x16 (row=lane&15, quad chunks) measured 0 in R3. (2) R4-R6 had a latent
//   WAR race (A0/B0(t+2) staged into rows still being read); R3's quadrant
//   A-map (rows mq*128 + wm*64 + ...) makes phase A cover ALL rows-0-127
//   reads, so phase B's same-buf stages are provably safe.
//   Per K-tile (reads = 24 b128/wave, LDS minimum; 64 MFMA 16x16x32/wave):
//    phA: issue B-nq0(4) B-nq1(4) A-mq0-lo(4) | stage A1,B1(t+1)->buf^1 |
//         [pin] A-mq0-hi(4); lgkm(4) -> MFMA i{0,1}x4n x2k (16);
//         lgkm(0) -> MFMA i{2,3} (16); barrier.
//    phB: issue A-mq1-lo(4) | stage A0,B0(t+2)->buf | [pin] A-mq1-hi(4);
//         lgkm(4) -> MFMA (16); lgkm(0) -> MFMA (16); VM4; barrier.
//   Safety: phB same-buf stages hit A rows 0-127 (= all waves' mq0 reads,
//   done at phA barrier since lgkm(0) precedes arrival) and B rows 0-127
//   (nq0, read in phA); phB reads rows 128-255 only -> disjoint. VM4 leaves
//   exactly {A0,B0(t+2)} in flight -> t+1 fully landed before its reads.
//   lgkm counting relies on DS-queue FIFO order; sched_barrier(0) pins the
//   issue-group boundaries and fences MFMA hoisting (rule #18).
//   LDS chunk-XOR swizzle (R3-proven): chunk c of row r at c ^ (r&7),
//   pre-swizzled global source, linear LDS dest; read chunks
//   c0=(quad^(fm&7))*8, c1=((quad+4)^(fm&7))*8.
// ---------------------------------------------------------------------------
#define NOPV ((void)0)
#define VM4 asm volatile("s_waitcnt vmcnt(4)" ::: "memory")
#define VM0 asm volatile("s_waitcnt vmcnt(0)" ::: "memory")
#define LGKM4 asm volatile("s_waitcnt lgkmcnt(4)" ::: "memory")
#define LGKM0 asm volatile("s_waitcnt lgkmcnt(0)" ::: "memory")
#define SCHED0 __builtin_amdgcn_sched_barrier(0)
#define PRIO1 __builtin_amdgcn_s_setprio(1)
#define PRIO0 __builtin_amdgcn_s_setprio(0)

#define STAGE_A(BUF, H, KT) do {                                                  \
    lds16(Ag + (size_t)((H) * 128 +  0) * K_DIM + (size_t)(KT) * 64,              \
          &sA[BUF][(H) * 128 +  0 + wave * 8][0]);                                \
    lds16(Ag + (size_t)((H) * 128 + 64) * K_DIM + (size_t)(KT) * 64,              \
          &sA[BUF][(H) * 128 + 64 + wave * 8][0]);                                \
} while (0)

#define STAGE_B(BUF, H, KT) do {                                                  \
    lds16(Bg + (size_t)((H) * 128 +  0) * K_DIM + (size_t)(KT) * 64,              \
          &sB[BUF][(H) * 128 +  0 + wave * 8][0]);                                \
    lds16(Bg + (size_t)((H) * 128 + 64) * K_DIM + (size_t)(KT) * 64,              \
          &sB[BUF][(H) * 128 + 64 + wave * 8][0]);                                \
} while (0)

// A fragments: rows MQ*128 + wm*64 + i*16 + fm; i in {H*2, H*2+1}; ks 0,1
#define DS_A2(BUF, MQ, H) do {                                                    \
    _Pragma("unroll")                                                             \
    for (int i_ = (H) * 2; i_ < (H) * 2 + 2; ++i_) {                              \
        const u16* p_ = &sA[BUF][(MQ) * 128 + wm * 64 + i_ * 16 + fm][0];         \
        af[i_][0] = *(const short8*)(p_ + c0);                                    \
        af[i_][1] = *(const short8*)(p_ + c1);                                    \
    }                                                                             \
} while (0)

// B fragments: rows NQ*128 + wn*32 + j*16 + fm; j 0,1; ks 0,1
#define DS_B(BUF, NQ, ARR) do {                                                   \
    _Pragma("unroll")                                                             \
    for (int j_ = 0; j_ < 2; ++j_) {                                              \
        const u16* p_ = &sB[BUF][(NQ) * 128 + wn * 32 + j_ * 16 + fm][0];         \
        ARR[j_][0] = *(const short8*)(p_ + c0);                                   \
        ARR[j_][1] = *(const short8*)(p_ + c1);                                   \
    }                                                                             \
} while (0)

// MFMA cluster: m-frags {H*2, H*2+1} of quadrant MQ x all 4 n x 2 ksteps = 16
#define MFMA_I2(MQ, H) do {                                                       \
    _Pragma("unroll")                                                             \
    for (int i_ = (H) * 2; i_ < (H) * 2 + 2; ++i_) {                              \
        _Pragma("unroll")                                                         \
        for (int j_ = 0; j_ < 2; ++j_) {                                          \
            _Pragma("unroll")                                                     \
            for (int k_ = 0; k_ < 2; ++k_) {                                      \
                acc[(MQ) * 4 + i_][j_] =                                          \
                    __builtin_amdgcn_mfma_f32_16x16x32_bf16(                      \
                        af[i_][k_], b0f[j_][k_], acc[(MQ) * 4 + i_][j_], 0, 0, 0);\
                acc[(MQ) * 4 + i_][2 + j_] =                                      \
                    __builtin_amdgcn_mfma_f32_16x16x32_bf16(                      \
                        af[i_][k_], b1f[j_][k_], acc[(MQ) * 4 + i_][2 + j_],      \
                        0, 0, 0);                                                 \
            }                                                                     \
        }                                                                         \
    }                                                                             \
} while (0)

// phase A (quadrant mq0 + all B): 16 reads, 32 MFMA, 1 barrier
#define PH_A(BUF, STAGE_STMT) do {                                                \
    DS_B(BUF, 0, b0f);                                                            \
    DS_B(BUF, 1, b1f);                                                            \
    DS_A2(BUF, 0, 0);                                                             \
    STAGE_STMT;                                                                   \
    SCHED0;                                                                       \
    DS_A2(BUF, 0, 1);                                                             \
    LGKM4; SCHED0;                                                                \
    PRIO1; MFMA_I2(0, 0); PRIO0;                                                  \
    LGKM0; SCHED0;                                                                \
    PRIO1; MFMA_I2(0, 1); PRIO0;                                                  \
    asm volatile("" ::: "memory");                                                \
    __builtin_amdgcn_s_barrier();                                                 \
} while (0)

// phase B (quadrant mq1, reuse b0f/b1f): 8 reads, 32 MFMA, [vm], 1 barrier
#define PH_B(BUF, STAGE_STMT, WAIT_STMT) do {                                     \
    DS_A2(BUF, 1, 0);                                                             \
    STAGE_STMT;                                                                   \
    SCHED0;                                                                       \
    DS_A2(BUF, 1, 1);                                                             \
    LGKM4; SCHED0;                                                                \
    PRIO1; MFMA_I2(1, 0); PRIO0;                                                  \
    LGKM0; SCHED0;                                                                \
    PRIO1; MFMA_I2(1, 1); PRIO0;                                                  \
    WAIT_STMT;                                                                    \
    asm volatile("" ::: "memory");                                                \
    __builtin_amdgcn_s_barrier();                                                 \
} while (0)

__global__ __launch_bounds__(512, 2) void gemm_bt(
    const u16* __restrict__ A,
    const u16* __restrict__ Bt,
    float* __restrict__ C) {
    __shared__ __align__(16) u16 sA[2][256][64];  // 64 KB
    __shared__ __align__(16) u16 sB[2][256][64];  // 64 KB

    const int tid  = threadIdx.x;
    const int wave = tid >> 6;
    const int lane = tid & 63;
    const int wm = wave >> 2;     // 0..1 (M)
    const int wn = wave & 3;      // 0..3 (N)

    // XCD-aware bijective swizzle of the 128 (m,n) tiles per batch
    int wg  = blockIdx.y * 8 + blockIdx.x;          // 0..127
    int swz = (wg & 7) * 16 + (wg >> 3);
    const int bn0 = (swz & 7) * 256;
    const int bm0 = (swz >> 3) * 256;
    const int bat = blockIdx.z;

    // staging: lane covers row (lane>>3) of an 8-row group; global 16B chunk
    // is (lane&7) ^ (lane>>3)  [pre-swizzled source, linear LDS dest]
    const int slr = lane >> 3;
    const int slc = ((lane & 7) ^ slr) * 8;
    const u16* Ag = A + (size_t)(bm0 + wave * 8 + slr) * K_DIM + slc;
    const u16* Bg = Bt + (size_t)bat * N_DIM * K_DIM
                      + (size_t)(bn0 + wave * 8 + slr) * K_DIM + slc;

    // 16x16x32 fragment decomposition (R3-verified, 0 bank conflicts)
    const int fm   = lane & 15;
    const int quad = lane >> 4;
    const int c0   = ((quad     ^ (fm & 7)) * 8);   // K-step 0 chunk (elems)
    const int c1   = (((quad + 4) ^ (fm & 7)) * 8); // K-step 1 chunk

    f32x4 acc[8][4] = {};   // [mq*4+i][nq*2+j], 128 regs (AGPR)
    short8 af[4][2];        // A frags of current quadrant [i][ks]  (32 VGPR)
    short8 b0f[2][2];       // B nq0, live phA -> phB               (16 VGPR)
    short8 b1f[2][2];       // B nq1, live phA -> phB               (16 VGPR)

    // prologue: t0 fully + t1 halves A0,B0 (12 loads/wave); VM4 -> t0 landed.
    STAGE_A(0, 0, 0); STAGE_B(0, 0, 0);
    STAGE_A(0, 1, 0); STAGE_B(0, 1, 0);
    STAGE_A(1, 0, 1); STAGE_B(1, 0, 1);
    VM4;
    __builtin_amdgcn_s_barrier();

#pragma unroll 1
    for (int t = 0; t <= 60; t += 2) {
        // tile t (buf0)
        PH_A(0, { STAGE_A(1, 1, t + 1); STAGE_B(1, 1, t + 1); });
        PH_B(0, { STAGE_A(0, 0, t + 2); STAGE_B(0, 0, t + 2); }, VM4);
        // tile t+1 (buf1)
        PH_A(1, { STAGE_A(0, 1, t + 2); STAGE_B(0, 1, t + 2); });
        PH_B(1, { STAGE_A(1, 0, t + 3); STAGE_B(1, 0, t + 3); }, VM4);
    }
    // peel t = 62 (buf0): finish staging t63 halves A1/B1, then drain fully
    PH_A(0, { STAGE_A(1, 1, 63); STAGE_B(1, 1, 63); });
    PH_B(0, NOPV, VM0);
    // peel t = 63 (buf1): nothing left to stage
    PH_A(1, NOPV);
    PH_B(1, NOPV, NOPV);

    // epilogue: C/D layout col = lane&15 (n), row = quad*4 + r (m89-verified)
    float* Cb = C + (size_t)bat * M_DIM * N_DIM;
#pragma unroll
    for (int a = 0; a < 8; ++a) {
        const int mq = a >> 2, i = a & 3;
        const int m0 = bm0 + mq * 128 + wm * 64 + i * 16 + quad * 4;
#pragma unroll
        for (int b = 0; b < 4; ++b) {
            const int nq = b >> 1, j = b & 1;
            const int n = bn0 + nq * 128 + wn * 32 + j * 16 + fm;
#pragma unroll
            for (int r = 0; r < 4; ++r)
                Cb[(size_t)(m0 + r) * N_DIM + n] = acc[a][b][r];
        }
    }
}

extern "C" void kernel_launch(void* const* d_in, const int* in_sizes, int n_in,
                              void* d_out, int out_size, void* d_ws, size_t ws_size,
                              hipStream_t stream) {
    const float* x    = (const float*)d_in[0];
    const float* vals = (const float*)d_in[1];
    // d_in[2] = row_offsets (structure fixed: row i starts at i*409)
    const int*   cols = (const int*)d_in[3];
    float* out = (float*)d_out;

    // workspace: [ W bf16 : 32 MB ][ Xb bf16 : 64 MB ]
    u16* W  = (u16*)d_ws;
    u16* Xb = (u16*)d_ws + (size_t)M_DIM * K_DIM;

    int n8 = (B_DIM * N_DIM * K_DIM) / 8;  // 4,194,304 threads
    cvt_x<<<dim3(n8 / 256), dim3(256), 0, stream>>>(x, Xb);

    scatter_w<<<dim3(M_DIM), dim3(256), 0, stream>>>(vals, cols, W);

    dim3 grid(N_DIM / 256, M_DIM / 256, B_DIM);
    gemm_bt<<<grid, dim3(512), 0, stream>>>(W, Xb, out);
}